// Round 2
// baseline (4239.449 us; speedup 1.0000x reference)
//
#include <hip/hip_runtime.h>
#include <math.h>

#define B_ROWS 1024
#define DIM 1024
#define N_TRAIN 100000
#define TOPK 20
#define CAND 32      // phase-1 candidates kept per row (rescored exactly in phase 2)
#define PT_L 12      // per-thread streaming list depth in topk_kernel
#define NCLS 1000
#define TEMP 0.07

typedef __attribute__((ext_vector_type(8))) short short8;
typedef __attribute__((ext_vector_type(4))) float f32x4;

// Pack two fp32 -> two bf16 (round-to-nearest-ish via +0x8000 on magnitude bits).
__device__ __forceinline__ unsigned cvt2_bf16(float lo, float hi) {
  unsigned ul = __float_as_uint(lo) + 0x8000u;
  unsigned uh = __float_as_uint(hi) + 0x8000u;
  return (ul >> 16) | (uh & 0xFFFF0000u);
}

// ---------------- reciprocal row norms (fp32, phase-1 scaling only) ----------------
__global__ __launch_bounds__(256) void norm_kernel(const float* __restrict__ f,
                                                   const float* __restrict__ tf,
                                                   float* __restrict__ rnf,
                                                   float* __restrict__ rnt) {
  int row = blockIdx.x;
  int t = threadIdx.x;
  const float4* src;
  if (row < B_ROWS) src = (const float4*)(f + (size_t)row * DIM);
  else              src = (const float4*)(tf + (size_t)(row - B_ROWS) * DIM);
  float4 v = src[t];  // 256 threads * 4 floats = 1024 = DIM
  float s = v.x * v.x + v.y * v.y + v.z * v.z + v.w * v.w;
#pragma unroll
  for (int off = 32; off > 0; off >>= 1) s += __shfl_down(s, off);
  __shared__ float wsum[4];
  if ((t & 63) == 0) wsum[t >> 6] = s;
  __syncthreads();
  if (t == 0) {
    float tot = wsum[0] + wsum[1] + wsum[2] + wsum[3];
    float r = 1.0f / sqrtf(tot);
    if (row < B_ROWS) rnf[row] = r;
    else              rnt[row - B_ROWS] = r;
  }
}

// ---------------- phase-1 bf16 MFMA GEMM: sim[b, n] ~= (f_b . tf_n) * rnf[b] * rnt[n] ----------------
// 128x128 tile, BK=32, 256 threads = 4 waves, each wave a 64x64 quadrant of 4x4 16x16x32 MFMAs.
__global__ __launch_bounds__(256) void gemm_kernel(
    const float* __restrict__ f, const float* __restrict__ tf,
    const float* __restrict__ rnf, const float* __restrict__ rnt,
    float* __restrict__ simbuf, int c0, int ncols, int ncld) {
  __shared__ __align__(16) unsigned short As[128 * 32];
  __shared__ __align__(16) unsigned short Bs[128 * 32];

  const int t = threadIdx.x;
  const int bm0 = blockIdx.x * 128;   // M tile (8 tiles cover B_ROWS)
  const int bn0 = blockIdx.y * 128;   // N tile within chunk
  const int l = t & 63;
  const int w = t >> 6;
  const int qm = (w >> 1) * 64;
  const int qn = (w & 1) * 64;
  const int lm = l & 15;
  const int kg = l >> 4;

  // staging: unit = 8 consecutive k-elems (one 16B bf16 LDS write); 4 units/row, 512 units/tile
  const int u0 = t;
  const int u1 = t + 256;
  const int rA0 = u0 >> 2, cA0 = (u0 & 3) * 8;
  const int rA1 = u1 >> 2, cA1 = (u1 & 3) * 8;

  const long long fbase0 = (long long)(bm0 + rA0) * DIM + cA0;
  const long long fbase1 = (long long)(bm0 + rA1) * DIM + cA1;
  const int n0 = c0 + bn0 + rA0;
  const int n1 = c0 + bn0 + rA1;
  const bool v0 = n0 < N_TRAIN;
  const bool v1 = n1 < N_TRAIN;
  const long long tbase0 = (long long)n0 * DIM + cA0;
  const long long tbase1 = (long long)n1 * DIM + cA1;

  f32x4 acc[4][4] = {};

  for (int k0 = 0; k0 < DIM; k0 += 32) {
    float4 a0 = *(const float4*)(f + fbase0 + k0);
    float4 a1 = *(const float4*)(f + fbase0 + k0 + 4);
    float4 a2 = *(const float4*)(f + fbase1 + k0);
    float4 a3 = *(const float4*)(f + fbase1 + k0 + 4);
    float4 z = make_float4(0.f, 0.f, 0.f, 0.f);
    float4 b0 = v0 ? *(const float4*)(tf + tbase0 + k0) : z;
    float4 b1 = v0 ? *(const float4*)(tf + tbase0 + k0 + 4) : z;
    float4 b2 = v1 ? *(const float4*)(tf + tbase1 + k0) : z;
    float4 b3 = v1 ? *(const float4*)(tf + tbase1 + k0 + 4) : z;

    __syncthreads();  // previous iteration's fragment reads complete

    uint4 pa0, pa1, pb0, pb1;
    pa0.x = cvt2_bf16(a0.x, a0.y); pa0.y = cvt2_bf16(a0.z, a0.w);
    pa0.z = cvt2_bf16(a1.x, a1.y); pa0.w = cvt2_bf16(a1.z, a1.w);
    pa1.x = cvt2_bf16(a2.x, a2.y); pa1.y = cvt2_bf16(a2.z, a2.w);
    pa1.z = cvt2_bf16(a3.x, a3.y); pa1.w = cvt2_bf16(a3.z, a3.w);
    pb0.x = cvt2_bf16(b0.x, b0.y); pb0.y = cvt2_bf16(b0.z, b0.w);
    pb0.z = cvt2_bf16(b1.x, b1.y); pb0.w = cvt2_bf16(b1.z, b1.w);
    pb1.x = cvt2_bf16(b2.x, b2.y); pb1.y = cvt2_bf16(b2.z, b2.w);
    pb1.z = cvt2_bf16(b3.x, b3.y); pb1.w = cvt2_bf16(b3.z, b3.w);
    *(uint4*)&As[u0 * 8] = pa0;
    *(uint4*)&As[u1 * 8] = pa1;
    *(uint4*)&Bs[u0 * 8] = pb0;
    *(uint4*)&Bs[u1 * 8] = pb1;

    __syncthreads();

    short8 af[4], bfr[4];
#pragma unroll
    for (int mi = 0; mi < 4; ++mi)
      af[mi] = *(const short8*)&As[(qm + mi * 16 + lm) * 32 + kg * 8];
#pragma unroll
    for (int ni = 0; ni < 4; ++ni)
      bfr[ni] = *(const short8*)&Bs[(qn + ni * 16 + lm) * 32 + kg * 8];
#pragma unroll
    for (int mi = 0; mi < 4; ++mi)
#pragma unroll
      for (int ni = 0; ni < 4; ++ni)
        acc[mi][ni] = __builtin_amdgcn_mfma_f32_16x16x32_bf16(af[mi], bfr[ni], acc[mi][ni], 0, 0, 0);
  }

  // epilogue: C/D layout col = lane&15, row = (lane>>4)*4 + reg
#pragma unroll
  for (int mi = 0; mi < 4; ++mi) {
#pragma unroll
    for (int r = 0; r < 4; ++r) {
      int gb = bm0 + qm + mi * 16 + kg * 4 + r;
      float sf = rnf[gb];
#pragma unroll
      for (int ni = 0; ni < 4; ++ni) {
        int colc = bn0 + qn + ni * 16 + lm;
        int gn = c0 + colc;
        if (gn < N_TRAIN) {
          simbuf[(size_t)gb * ncld + colc] = acc[mi][ni][r] * sf * rnt[gn];
        }
      }
    }
  }
}

// ---------------- exact chunk top-CAND + merge into running top-CAND ----------------
__global__ __launch_bounds__(256) void topk_kernel(
    const float* __restrict__ simbuf, int ncld, int ncols, int c0, int first,
    float* __restrict__ topv, int* __restrict__ topi) {
  const int b = blockIdx.x;
  const int t = threadIdx.x;
  const float* row = simbuf + (size_t)b * ncld;

  float lv[PT_L]; int li[PT_L];
#pragma unroll
  for (int i = 0; i < PT_L; ++i) { lv[i] = -INFINITY; li[i] = 0x7FFFFFFF; }

  for (int j = t; j < ncols; j += 256) {
    float v = row[j];
    if (v > lv[PT_L - 1]) {
      lv[PT_L - 1] = v; li[PT_L - 1] = c0 + j;
#pragma unroll
      for (int i = PT_L - 1; i > 0; --i) {
        if (lv[i] > lv[i - 1]) {
          float tv = lv[i]; lv[i] = lv[i - 1]; lv[i - 1] = tv;
          int ti = li[i]; li[i] = li[i - 1]; li[i - 1] = ti;
        }
      }
    }
  }

  __shared__ float cv[256 * PT_L];
  __shared__ int ci[256 * PT_L];
#pragma unroll
  for (int i = 0; i < PT_L; ++i) { cv[i * 256 + t] = lv[i]; ci[i * 256 + t] = li[i]; }

  __shared__ float outv[CAND]; __shared__ int outi[CAND];
  __shared__ float rv[4]; __shared__ int rti[4]; __shared__ int rsl[4];
  __syncthreads();

  for (int round = 0; round < CAND; ++round) {
    float bv = -INFINITY; int bi = 0x7FFFFFFF; int bs = -1;
#pragma unroll
    for (int i = 0; i < PT_L; ++i) {
      int s = i * 256 + t;
      float v = cv[s]; int ix = ci[s];
      if (v > bv || (v == bv && ix < bi)) { bv = v; bi = ix; bs = s; }
    }
#pragma unroll
    for (int off = 32; off > 0; off >>= 1) {
      float ov = __shfl_down(bv, off);
      int oi = __shfl_down(bi, off);
      int os = __shfl_down(bs, off);
      if (ov > bv || (ov == bv && oi < bi)) { bv = ov; bi = oi; bs = os; }
    }
    if ((t & 63) == 0) { rv[t >> 6] = bv; rti[t >> 6] = bi; rsl[t >> 6] = bs; }
    __syncthreads();
    if (t == 0) {
      float fbv = rv[0]; int fbi = rti[0]; int fbs = rsl[0];
      for (int w2 = 1; w2 < 4; ++w2)
        if (rv[w2] > fbv || (rv[w2] == fbv && rti[w2] < fbi)) { fbv = rv[w2]; fbi = rti[w2]; fbs = rsl[w2]; }
      outv[round] = fbv; outi[round] = fbi;
      if (fbs >= 0) cv[fbs] = -INFINITY;
    }
    __syncthreads();
  }

  if (t == 0) {
    float mv[CAND]; int mi_[CAND];
    if (first) {
      for (int i = 0; i < CAND; ++i) { mv[i] = outv[i]; mi_[i] = outi[i]; }
    } else {
      int p = 0, q = 0;
      for (int i = 0; i < CAND; ++i) {
        float av = topv[b * CAND + p]; int ai = topi[b * CAND + p];
        float bv2 = outv[q]; int bi2 = outi[q];
        bool takeA = (av > bv2) || (av == bv2 && ai < bi2);  // ties: lower index first
        if (takeA) { mv[i] = av; mi_[i] = ai; ++p; }
        else       { mv[i] = bv2; mi_[i] = bi2; ++q; }
      }
    }
    for (int i = 0; i < CAND; ++i) { topv[b * CAND + i] = mv[i]; topi[b * CAND + i] = mi_[i]; }
  }
}

// ---------------- phase-2: fp64 exact rescore of CAND candidates + softmax + votes ----------------
__global__ __launch_bounds__(256) void rescore_vote_kernel(
    const float* __restrict__ f, const float* __restrict__ tf,
    const int* __restrict__ topi, const int* __restrict__ labels,
    float* __restrict__ out) {
  const int b = blockIdx.x;
  const int t = threadIdx.x;
  const int l = t & 63, w = t >> 6;
  __shared__ __align__(16) float fs[DIM];
  __shared__ double cd[CAND];   // raw dot, fp64
  __shared__ double cn[CAND];   // candidate row |.|^2, fp64
  __shared__ double wred[4];

  // load f row into LDS; accumulate |f|^2 in fp64
  float4 v = ((const float4*)(f + (size_t)b * DIM))[t];
  ((float4*)fs)[t] = v;
  double p = (double)v.x * v.x + (double)v.y * v.y + (double)v.z * v.z + (double)v.w * v.w;
#pragma unroll
  for (int off = 32; off > 0; off >>= 1) p += __shfl_down(p, off);
  if (l == 0) wred[w] = p;
  __syncthreads();
  double f2 = wred[0] + wred[1] + wred[2] + wred[3];

  // wave w rescores candidates w, w+4, ...
  for (int c = w; c < CAND; c += 4) {
    int idx = topi[b * CAND + c];
    const float4* trow = (const float4*)(tf + (size_t)idx * DIM);
    double dot = 0.0, n2 = 0.0;
#pragma unroll
    for (int j = 0; j < 4; ++j) {
      float4 tv = trow[j * 64 + l];
      float4 fv = ((const float4*)fs)[j * 64 + l];
      dot += (double)tv.x * fv.x + (double)tv.y * fv.y + (double)tv.z * fv.z + (double)tv.w * fv.w;
      n2  += (double)tv.x * tv.x + (double)tv.y * tv.y + (double)tv.z * tv.z + (double)tv.w * tv.w;
    }
#pragma unroll
    for (int off = 32; off > 0; off >>= 1) {
      dot += __shfl_down(dot, off);
      n2  += __shfl_down(n2, off);
    }
    if (l == 0) { cd[c] = dot; cn[c] = n2; }
  }

  __shared__ float a10[NCLS], a20[NCLS];
  for (int c = t; c < NCLS; c += 256) { a10[c] = 0.f; a20[c] = 0.f; }
  __syncthreads();  // orders cd/cn writes and histogram zero before thread-0 stage

  if (t == 0) {
    double rf = 1.0 / sqrt(f2);
    double sv[CAND]; int si[CAND];
    for (int c = 0; c < CAND; ++c) {
      sv[c] = cd[c] * rf / sqrt(cn[c]);
      si[c] = topi[b * CAND + c];
    }
    // insertion sort: value desc, index asc on ties (matches lax.top_k)
    for (int i = 1; i < CAND; ++i) {
      double kv = sv[i]; int ki = si[i]; int j = i - 1;
      while (j >= 0 && (sv[j] < kv || (sv[j] == kv && si[j] > ki))) {
        sv[j + 1] = sv[j]; si[j + 1] = si[j]; --j;
      }
      sv[j + 1] = kv; si[j + 1] = ki;
    }
    double m = sv[0], S = 0.0; double e[TOPK];
    for (int i = 0; i < TOPK; ++i) { e[i] = exp((sv[i] - m) / TEMP); S += e[i]; }
    double inv = 1.0 / S;
    for (int i = 0; i < TOPK; ++i) {
      float wgt = (float)(e[i] * inv);
      int cls = labels[si[i]];
      a20[cls] += wgt;
      if (i < 10) a10[cls] += wgt;
    }
  }
  __syncthreads();
  for (int c = t; c < NCLS; c += 256) {
    out[(size_t)b * NCLS + c] = a10[c];
    out[(size_t)(B_ROWS * NCLS) + (size_t)b * NCLS + c] = a20[c];
  }
}

extern "C" void kernel_launch(void* const* d_in, const int* in_sizes, int n_in,
                              void* d_out, int out_size, void* d_ws, size_t ws_size,
                              hipStream_t stream) {
  const float* f = (const float*)d_in[0];
  const float* tf = (const float*)d_in[1];
  const int* labels = (const int*)d_in[2];
  float* out = (float*)d_out;

  char* ws = (char*)d_ws;
  size_t off = 0;
  float* rnf = (float*)(ws + off); off += (size_t)B_ROWS * 4;
  off = (off + 255) & ~(size_t)255;
  float* rnt = (float*)(ws + off); off += (size_t)N_TRAIN * 4;
  off = (off + 255) & ~(size_t)255;
  float* topv = (float*)(ws + off); off += (size_t)B_ROWS * CAND * 4;
  int* topi = (int*)(ws + off); off += (size_t)B_ROWS * CAND * 4;
  off = (off + 255) & ~(size_t)255;
  float* simbuf = (float*)(ws + off);

  size_t avail = (ws_size > off) ? (ws_size - off) : 0;
  long long ncmax = (long long)(avail / ((size_t)B_ROWS * 4));
  int NC = (int)((ncmax / 128) * 128);
  if (NC > 12544) NC = 12544;  // 98 tiles, 51.4 MB sim buffer
  if (NC < 128) NC = 128;

  norm_kernel<<<B_ROWS + N_TRAIN, 256, 0, stream>>>(f, tf, rnf, rnt);

  int nchunks = (N_TRAIN + NC - 1) / NC;
  for (int c = 0; c < nchunks; ++c) {
    int c0 = c * NC;
    int ncols = N_TRAIN - c0; if (ncols > NC) ncols = NC;
    int ntiles = (ncols + 127) / 128;
    dim3 grid(8, ntiles);  // M-tiles fastest: 8 blocks sharing one tf tile dispatch adjacently (LLC reuse)
    gemm_kernel<<<grid, 256, 0, stream>>>(f, tf, rnf, rnt, simbuf, c0, ncols, NC);
    topk_kernel<<<B_ROWS, 256, 0, stream>>>(simbuf, NC, ncols, c0, c == 0 ? 1 : 0, topv, topi);
  }

  rescore_vote_kernel<<<B_ROWS, 256, 0, stream>>>(f, tf, topi, labels, out);
}

// Round 3
// 1729.131 us; speedup vs baseline: 2.4518x; 2.4518x over previous
//
#include <hip/hip_runtime.h>
#include <math.h>

#define B_ROWS 1024
#define DIM 1024
#define N_TRAIN 100000
#define TOPK 20
#define CAND 32      // phase-1 candidates per row (rescored exactly in phase 2)
#define PT_L 8       // per-thread streaming list depth in topk_kernel
#define NCLS 1000
#define TEMP 0.07
#define NC_CAP 12544

typedef __attribute__((ext_vector_type(8))) short short8;
typedef __attribute__((ext_vector_type(4))) float f32x4;
typedef unsigned short ushort_t;

__device__ __forceinline__ ushort_t cvt1_bf16(float x) {
  return (ushort_t)((__float_as_uint(x) + 0x8000u) >> 16);
}
__device__ __forceinline__ float bf16_to_f(ushort_t u) {
  return __uint_as_float(((unsigned)u) << 16);
}

// async global->LDS, 16B per lane; LDS dest = wave-uniform base + lane*16
__device__ __forceinline__ void gl2lds16(const void* g, void* l) {
  __builtin_amdgcn_global_load_lds(
      (const __attribute__((address_space(1))) unsigned int*)g,
      (__attribute__((address_space(3))) unsigned int*)l, 16, 0, 0);
}

// ---------------- fused normalize + bf16 convert (one row per wave) ----------------
// src: fp32 [nrows][1024] starting at row row0; dst: bf16 [..][1024] at local row index
__global__ __launch_bounds__(256) void convert_kernel(const float* __restrict__ src,
                                                      ushort_t* __restrict__ dst,
                                                      int row0, int nrows) {
  const int w = threadIdx.x >> 6;
  const int l = threadIdx.x & 63;
  const int r = blockIdx.x * 4 + w;     // local row within [0, nrows)
  if (r >= nrows) return;
  const float4* s = (const float4*)(src + (size_t)(row0 + r) * DIM);
  float4 v[4];
  float ss = 0.f;
#pragma unroll
  for (int j = 0; j < 4; ++j) {
    v[j] = s[j * 64 + l];
    ss += v[j].x * v[j].x + v[j].y * v[j].y + v[j].z * v[j].z + v[j].w * v[j].w;
  }
#pragma unroll
  for (int off = 32; off > 0; off >>= 1) ss += __shfl_xor(ss, off);
  float rn = rsqrtf(ss);
  ushort_t* d = dst + (size_t)r * DIM;
#pragma unroll
  for (int j = 0; j < 4; ++j) {
    ushort4 o;
    o.x = cvt1_bf16(v[j].x * rn);
    o.y = cvt1_bf16(v[j].y * rn);
    o.z = cvt1_bf16(v[j].z * rn);
    o.w = cvt1_bf16(v[j].w * rn);
    *(ushort4*)(d + (size_t)(j * 64 + l) * 4) = o;
  }
}

// ---------------- m97-style bf16 MFMA GEMM: sim16[b, col] = f16_b . tf16_col ----------------
// 128x128 tile, BK=32, 4 waves, each wave 64x64 via 4x4 16x16x32 MFMAs, global_load_lds staging.
__global__ __launch_bounds__(256) void gemm_kernel(
    const ushort_t* __restrict__ a16,   // [1024][1024] normalized f, bf16
    const ushort_t* __restrict__ b16,   // [NC][1024] normalized tf chunk, bf16
    ushort_t* __restrict__ simbuf,      // [1024][ncld] bf16
    int ncld, int ncols) {
  __shared__ __align__(16) ushort_t As[128 * 32];
  __shared__ __align__(16) ushort_t Bs[128 * 32];

  const int t = threadIdx.x;
  const int bm0 = blockIdx.x * 128;
  const int bn0 = blockIdx.y * 128;
  const int l = t & 63;
  const int w = t >> 6;
  const int qm = (w >> 1) * 64;
  const int qn = (w & 1) * 64;
  const int lm = l & 15;
  const int kg = l >> 4;

  // staging: wave w, instr j in {0,1}: rows (w*2+j)*16 + (l>>2), k-bytes (l&3)*16
  const int srow = l >> 2;
  const int skb = (l & 3) * 16;
  const char* pa0 = (const char*)(a16 + (size_t)(bm0 + (w * 2 + 0) * 16 + srow) * DIM) + skb;
  const char* pa1 = (const char*)(a16 + (size_t)(bm0 + (w * 2 + 1) * 16 + srow) * DIM) + skb;
  const char* pb0 = (const char*)(b16 + (size_t)(bn0 + (w * 2 + 0) * 16 + srow) * DIM) + skb;
  const char* pb1 = (const char*)(b16 + (size_t)(bn0 + (w * 2 + 1) * 16 + srow) * DIM) + skb;
  ushort_t* lA0 = As + (w * 2 + 0) * 512;   // 512 ushort = 1024 B per wave-instr
  ushort_t* lA1 = As + (w * 2 + 1) * 512;
  ushort_t* lB0 = Bs + (w * 2 + 0) * 512;
  ushort_t* lB1 = Bs + (w * 2 + 1) * 512;

  f32x4 acc[4][4] = {};

  for (int k0 = 0; k0 < DIM; k0 += 32) {
    __syncthreads();   // previous iteration's fragment reads complete (WAR)
    const int kb = k0 * 2;
    gl2lds16(pa0 + kb, lA0);
    gl2lds16(pa1 + kb, lA1);
    gl2lds16(pb0 + kb, lB0);
    gl2lds16(pb1 + kb, lB1);
    __syncthreads();   // drains vmcnt (compiler emits vmcnt(0) before barrier)

    short8 af[4], bfr[4];
#pragma unroll
    for (int mi = 0; mi < 4; ++mi)
      af[mi] = *(const short8*)&As[(qm + mi * 16 + lm) * 32 + kg * 8];
#pragma unroll
    for (int ni = 0; ni < 4; ++ni)
      bfr[ni] = *(const short8*)&Bs[(qn + ni * 16 + lm) * 32 + kg * 8];
#pragma unroll
    for (int mi = 0; mi < 4; ++mi)
#pragma unroll
      for (int ni = 0; ni < 4; ++ni)
        acc[mi][ni] = __builtin_amdgcn_mfma_f32_16x16x32_bf16(af[mi], bfr[ni], acc[mi][ni], 0, 0, 0);
  }

  // epilogue: C/D layout col = lane&15, row = (lane>>4)*4 + reg; store bf16
#pragma unroll
  for (int mi = 0; mi < 4; ++mi) {
#pragma unroll
    for (int r = 0; r < 4; ++r) {
      int gb = bm0 + qm + mi * 16 + kg * 4 + r;
#pragma unroll
      for (int ni = 0; ni < 4; ++ni) {
        int colc = bn0 + qn + ni * 16 + lm;
        if (colc < ncols) simbuf[(size_t)gb * ncld + colc] = cvt1_bf16(acc[mi][ni][r]);
      }
    }
  }
}

// ---------------- chunk top-CAND (wave-local shuffle argmax) + merge into running list ----------------
__global__ __launch_bounds__(256) void topk_kernel(
    const ushort_t* __restrict__ simbuf, int ncld, int ncols, int c0, int first,
    float* __restrict__ topv, int* __restrict__ topi) {
  const int b = blockIdx.x;
  const int t = threadIdx.x;
  const int l = t & 63, w = t >> 6;
  const ushort_t* row = simbuf + (size_t)b * ncld;

  float lv[PT_L]; int li[PT_L];
#pragma unroll
  for (int i = 0; i < PT_L; ++i) { lv[i] = -INFINITY; li[i] = 0; }

  for (int j = t; j < ncols; j += 256) {
    float v = bf16_to_f(row[j]);
    if (v > lv[PT_L - 1]) {
      lv[PT_L - 1] = v; li[PT_L - 1] = c0 + j;
#pragma unroll
      for (int i = PT_L - 1; i > 0; --i) {
        if (lv[i] > lv[i - 1]) {
          float tv = lv[i]; lv[i] = lv[i - 1]; lv[i - 1] = tv;
          int ti = li[i]; li[i] = li[i - 1]; li[i - 1] = ti;
        }
      }
    }
  }

  // wave-local CAND rounds of shuffle argmax over per-lane sorted heads
  __shared__ float wv[4 * CAND];
  __shared__ int wi[4 * CAND];
  for (int r = 0; r < CAND; ++r) {
    float bv = lv[0]; int bi = li[0]; int bl = l;
#pragma unroll
    for (int off = 32; off > 0; off >>= 1) {
      float ov = __shfl_down(bv, off);
      int oi = __shfl_down(bi, off);
      int ol = __shfl_down(bl, off);
      if (ov > bv) { bv = ov; bi = oi; bl = ol; }
    }
    int wl = __shfl(bl, 0);
    if (l == 0) { wv[w * CAND + r] = bv; wi[w * CAND + r] = bi; }
    if (l == wl) {   // winner pops its head (static shift keeps list in registers)
#pragma unroll
      for (int i = 0; i < PT_L - 1; ++i) { lv[i] = lv[i + 1]; li[i] = li[i + 1]; }
      lv[PT_L - 1] = -INFINITY; li[PT_L - 1] = 0;
    }
  }
  __syncthreads();

  if (t == 0) {
    // merge 4 sorted-desc CAND lists -> chunk top-CAND
    float ov_[CAND]; int oi_[CAND];
    int p[4] = {0, 0, 0, 0};
    for (int i = 0; i < CAND; ++i) {
      int bw = -1; float bv = -INFINITY;
      for (int k = 0; k < 4; ++k)
        if (p[k] < CAND && wv[k * CAND + p[k]] > bv) { bv = wv[k * CAND + p[k]]; bw = k; }
      ov_[i] = bv; oi_[i] = wi[bw * CAND + p[bw]]; ++p[bw];
    }
    if (first) {
      for (int i = 0; i < CAND; ++i) { topv[b * CAND + i] = ov_[i]; topi[b * CAND + i] = oi_[i]; }
    } else {
      float mv[CAND]; int mi_[CAND];
      int pa = 0, q = 0;
      for (int i = 0; i < CAND; ++i) {
        float av = topv[b * CAND + pa];
        if (av >= ov_[q]) { mv[i] = av; mi_[i] = topi[b * CAND + pa]; ++pa; }
        else             { mv[i] = ov_[q]; mi_[i] = oi_[q]; ++q; }
      }
      for (int i = 0; i < CAND; ++i) { topv[b * CAND + i] = mv[i]; topi[b * CAND + i] = mi_[i]; }
    }
  }
}

// ---------------- phase-2: fp64 exact rescore of CAND candidates + softmax + votes ----------------
__global__ __launch_bounds__(256) void rescore_vote_kernel(
    const float* __restrict__ f, const float* __restrict__ tf,
    const int* __restrict__ topi, const int* __restrict__ labels,
    float* __restrict__ out) {
  const int b = blockIdx.x;
  const int t = threadIdx.x;
  const int l = t & 63, w = t >> 6;
  __shared__ __align__(16) float fs[DIM];
  __shared__ double cd[CAND];
  __shared__ double cn[CAND];
  __shared__ double wred[4];

  float4 v = ((const float4*)(f + (size_t)b * DIM))[t];
  ((float4*)fs)[t] = v;
  double p = (double)v.x * v.x + (double)v.y * v.y + (double)v.z * v.z + (double)v.w * v.w;
#pragma unroll
  for (int off = 32; off > 0; off >>= 1) p += __shfl_down(p, off);
  if (l == 0) wred[w] = p;
  __syncthreads();
  double f2 = wred[0] + wred[1] + wred[2] + wred[3];

  for (int c = w; c < CAND; c += 4) {
    int idx = topi[b * CAND + c];
    const float4* trow = (const float4*)(tf + (size_t)idx * DIM);
    double dot = 0.0, n2 = 0.0;
#pragma unroll
    for (int j = 0; j < 4; ++j) {
      float4 tv = trow[j * 64 + l];
      float4 fv = ((const float4*)fs)[j * 64 + l];
      dot += (double)tv.x * fv.x + (double)tv.y * fv.y + (double)tv.z * fv.z + (double)tv.w * fv.w;
      n2  += (double)tv.x * tv.x + (double)tv.y * tv.y + (double)tv.z * tv.z + (double)tv.w * tv.w;
    }
#pragma unroll
    for (int off = 32; off > 0; off >>= 1) {
      dot += __shfl_down(dot, off);
      n2  += __shfl_down(n2, off);
    }
    if (l == 0) { cd[c] = dot; cn[c] = n2; }
  }

  __shared__ float a10[NCLS], a20[NCLS];
  for (int c = t; c < NCLS; c += 256) { a10[c] = 0.f; a20[c] = 0.f; }
  __syncthreads();

  if (t == 0) {
    double rf = 1.0 / sqrt(f2);
    double sv[CAND]; int si[CAND];
    for (int c = 0; c < CAND; ++c) {
      sv[c] = cd[c] * rf / sqrt(cn[c]);
      si[c] = topi[b * CAND + c];
    }
    for (int i = 1; i < CAND; ++i) {   // sort: value desc, index asc on ties (matches lax.top_k)
      double kv = sv[i]; int ki = si[i]; int j = i - 1;
      while (j >= 0 && (sv[j] < kv || (sv[j] == kv && si[j] > ki))) {
        sv[j + 1] = sv[j]; si[j + 1] = si[j]; --j;
      }
      sv[j + 1] = kv; si[j + 1] = ki;
    }
    double m = sv[0], S = 0.0; double e[TOPK];
    for (int i = 0; i < TOPK; ++i) { e[i] = exp((sv[i] - m) / TEMP); S += e[i]; }
    double inv = 1.0 / S;
    for (int i = 0; i < TOPK; ++i) {
      float wgt = (float)(e[i] * inv);
      int cls = labels[si[i]];
      a20[cls] += wgt;
      if (i < 10) a10[cls] += wgt;
    }
  }
  __syncthreads();
  for (int c = t; c < NCLS; c += 256) {
    out[(size_t)b * NCLS + c] = a10[c];
    out[(size_t)(B_ROWS * NCLS) + (size_t)b * NCLS + c] = a20[c];
  }
}

extern "C" void kernel_launch(void* const* d_in, const int* in_sizes, int n_in,
                              void* d_out, int out_size, void* d_ws, size_t ws_size,
                              hipStream_t stream) {
  const float* f = (const float*)d_in[0];
  const float* tf = (const float*)d_in[1];
  const int* labels = (const int*)d_in[2];
  float* out = (float*)d_out;

  char* ws = (char*)d_ws;
  size_t off = 0;
  float* topv = (float*)(ws + off); off += (size_t)B_ROWS * CAND * 4;
  int* topi = (int*)(ws + off); off += (size_t)B_ROWS * CAND * 4;
  off = (off + 255) & ~(size_t)255;
  ushort_t* f16 = (ushort_t*)(ws + off); off += (size_t)B_ROWS * DIM * 2;
  off = (off + 255) & ~(size_t)255;

  // per-column cost: tf16 chunk (2048 B) + bf16 simbuf (2048 B)
  size_t avail = (ws_size > off) ? (ws_size - off) : 0;
  long long ncmax = (long long)(avail / 4096) - 64;  // slack for alignment
  int NC = (int)((ncmax / 128) * 128);
  if (NC > NC_CAP) NC = NC_CAP;
  if (NC < 128) NC = 128;

  ushort_t* tf16 = (ushort_t*)(ws + off); off += (size_t)NC * DIM * 2;
  off = (off + 255) & ~(size_t)255;
  ushort_t* simbuf = (ushort_t*)(ws + off);

  // normalize + convert f once: 1024 rows, 4 rows/block
  convert_kernel<<<B_ROWS / 4, 256, 0, stream>>>(f, f16, 0, B_ROWS);

  int nchunks = (N_TRAIN + NC - 1) / NC;
  for (int c = 0; c < nchunks; ++c) {
    int c0 = c * NC;
    int ncols = N_TRAIN - c0; if (ncols > NC) ncols = NC;
    int ntiles = (ncols + 127) / 128;
    convert_kernel<<<(ncols + 3) / 4, 256, 0, stream>>>(tf, tf16, c0, ncols);
    dim3 grid(8, ntiles);  // M fastest: 8 blocks share one B-tile back-to-back (L2 reuse)
    gemm_kernel<<<grid, 256, 0, stream>>>(f16, tf16, simbuf, NC, ncols);
    topk_kernel<<<B_ROWS, 256, 0, stream>>>(simbuf, NC, ncols, c0, c == 0 ? 1 : 0, topv, topi);
  }

  rescore_vote_kernel<<<B_ROWS, 256, 0, stream>>>(f, tf, topi, labels, out);
}